// Round 1
// baseline (452.079 us; speedup 1.0000x reference)
//
#include <hip/hip_runtime.h>
#include <stdint.h>

#define B_ 4
#define T_ 2048
#define D_ 1024
#define N_ 1024
#define TC 32
#define NCH (T_/TC)
#define KSQ 10

typedef __attribute__((ext_vector_type(4))) float f32x4;
typedef __attribute__((ext_vector_type(8))) short bf16x8;
typedef __attribute__((ext_vector_type(4))) unsigned short us4;

__device__ __forceinline__ unsigned short f2bf(float f){
  unsigned int u = __float_as_uint(f);
  return (unsigned short)((u + 0x7fffu + ((u >> 16) & 1u)) >> 16);
}
__device__ __forceinline__ float bf2f(unsigned short h){
  return __uint_as_float(((unsigned int)h) << 16);
}

__global__ void k_init(float* sc){
  int i = threadIdx.x;
  if (i < 64) sc[i] = 0.f;
}

__global__ void k_convert(const float* __restrict__ src, unsigned short* __restrict__ dst, int n4){
  int i = blockIdx.x * 256 + threadIdx.x;
  if (i >= n4) return;
  float4 v = ((const float4*)src)[i];
  us4 o;
  o.x = f2bf(v.x); o.y = f2bf(v.y); o.z = f2bf(v.z); o.w = f2bf(v.w);
  ((us4*)dst)[i] = o;
}

__device__ __forceinline__ void load_lds16(const unsigned short* g, unsigned short* l){
  __builtin_amdgcn_global_load_lds((const __attribute__((address_space(1))) void*)g,
                                   (__attribute__((address_space(3))) void*)l, 16, 0, 0);
}

// C[M,N] = (A[M,K] * B[N,K]^T) * outscale
// SQMODE: gridDim.z=2, B:=A (symmetric squaring chain), trace of scaled output
//         accumulated into sc[8+2*step+z] via diagonal-block atomics;
//         input scale read from sc[8+2*(step-1)+z] (1/t^2), step 0 = gram (scale 1).
// non-SQ: step>=0 -> outscale = sc[step], step<0 -> 1.0
template<int OUTBF16, int SQMODE>
__global__ __launch_bounds__(256) void k_gemm(
    const unsigned short* __restrict__ A0,
    const unsigned short* __restrict__ B0,
    void* __restrict__ C0,
    const unsigned short* __restrict__ A1,
    void* __restrict__ C1,
    int M, int N, int K,
    float* __restrict__ sc, int step)
{
  __shared__ alignas(16) unsigned short As[128*64];
  __shared__ alignas(16) unsigned short Bs[128*64];
  const int tid = threadIdx.x;
  const int wid = tid >> 6;
  const int lane = tid & 63;
  const int bn = blockIdx.x, bm = blockIdx.y;

  const unsigned short* A = A0;
  const unsigned short* Bmat = B0;
  char* C = (char*)C0;
  if (SQMODE){
    if (blockIdx.z){ A = A1; C = (char*)C1; }
    Bmat = A;
  }
  float outscale = 1.f;
  if (SQMODE){
    if (step > 0){ float t = sc[8 + (step-1)*2 + blockIdx.z]; outscale = 1.f/(t*t); }
  } else if (step >= 0){
    outscale = sc[step];
  }

  const int wr = wid >> 1, wc = wid & 1;    // wave 64x64 sub-tile
  const int rg = lane >> 3;                 // 0..7 row within 8-row staging group
  const int cby = (lane & 7) << 4;          // linear byte col within 128B row
  const int srow0 = wid * 32;
  const int frow = lane & 15;
  const int kgrp = lane >> 4;

  const size_t Abase = (size_t)bm * 128 * K;
  const size_t Bbase = (size_t)bn * 128 * K;

  f32x4 acc[4][4] = {};

  for (int kt = 0; kt < K; kt += 64){
    // stage A,B tiles (128x64 bf16 each), XOR-swizzled via pre-swizzled global src
    #pragma unroll
    for (int i = 0; i < 4; i++){
      int r = srow0 + i*8 + rg;
      int cb = cby ^ ((r & 7) << 4);
      load_lds16(A    + Abase + (size_t)r*K + kt + (cb >> 1), As + (srow0 + i*8)*64);
      load_lds16(Bmat + Bbase + (size_t)r*K + kt + (cb >> 1), Bs + (srow0 + i*8)*64);
    }
    __syncthreads();
    #pragma unroll
    for (int kk = 0; kk < 2; kk++){
      const int kbyte = kk*64 + kgrp*16;
      bf16x8 af[4], bfv[4];
      #pragma unroll
      for (int m = 0; m < 4; m++){
        int r = wr*64 + m*16 + frow;
        int cb = kbyte ^ ((r & 7) << 4);
        af[m] = *(const bf16x8*)((const char*)As + r*128 + cb);
      }
      #pragma unroll
      for (int n2 = 0; n2 < 4; n2++){
        int r = wc*64 + n2*16 + frow;
        int cb = kbyte ^ ((r & 7) << 4);
        bfv[n2] = *(const bf16x8*)((const char*)Bs + r*128 + cb);
      }
      #pragma unroll
      for (int m = 0; m < 4; m++){
        #pragma unroll
        for (int n2 = 0; n2 < 4; n2++){
          acc[m][n2] = __builtin_amdgcn_mfma_f32_16x16x32_bf16(af[m], bfv[n2], acc[m][n2], 0, 0, 0);
        }
      }
    }
    __syncthreads();
  }

  const int row0 = bm*128 + wr*64;
  const int col0 = bn*128 + wc*64 + frow;
  #pragma unroll
  for (int m = 0; m < 4; m++){
    #pragma unroll
    for (int n2 = 0; n2 < 4; n2++){
      const int col = col0 + n2*16;
      const int rb = row0 + m*16 + kgrp*4;
      #pragma unroll
      for (int j = 0; j < 4; j++){
        float v = acc[m][n2][j] * outscale;
        if (OUTBF16) ((unsigned short*)C)[(size_t)(rb + j)*N + col] = f2bf(v);
        else         ((float*)C)[(size_t)(rb + j)*N + col] = v;
      }
    }
  }
  if (SQMODE && bm == bn && wr == wc){
    int j = frow - kgrp*4;
    if (j >= 0 && j < 4){
      float d = 0.f;
      #pragma unroll
      for (int m = 0; m < 4; m++) d += acc[m][m][j];
      atomicAdd(&sc[8 + step*2 + blockIdx.z], d * outscale);
    }
  }
}

__global__ void k_final(float* sc){
  int z = threadIdx.x;
  if (z < 2){
    float ll = 0.f;
    float w = 1.f;
    for (int i = 0; i <= KSQ; i++){
      ll += w * __logf(sc[8 + 2*i + z]);
      w *= 0.5f;
    }
    float sig = __expf(0.5f * ll);     // sigma = sqrt(lambda_max)
    sig = fmaxf(sig, 1e-5f);
    sc[z] = 1.f / fmaxf(sig, 1.f);     // inv scale
  }
}

__device__ __forceinline__ float softplusf(float x){
  return (x > 0.f) ? (x + __logf(1.f + __expf(-x))) : __logf(1.f + __expf(x));
}
__device__ __forceinline__ float tanhfastf(float x){
  float e = __expf(2.f * x);
  return 1.f - 2.f/(e + 1.f);
}
__device__ __forceinline__ void abc_from(float pin, float draw, float braw, float craw,
    float alpha, float ginv, float& a_o, float& bu_o, float& c_o){
  float sp = softplusf(draw);
  float av = __expf(-sp * alpha);
  av = fminf(av, 1.f - 1e-4f);
  float bv = tanhfastf(braw);
  float cv = tanhfastf(craw);
  float p = av*av + cv*cv;
  float r = bv*bv;
  float q = av*bv;
  float pr = p - r;
  float disc = pr*pr + 4.f*q*q;
  float lam = 0.5f*(p + r + sqrtf(disc + 1e-12f));
  float sig = sqrtf(lam + 1e-12f);
  float inv = 1.f / fmaxf(sig, 1.f);
  a_o = av * inv;
  c_o = cv * inv;
  bu_o = (bv * inv) * (pin * ginv);
}

// P cols: [0,N)=P_in, [N,2N)=delta_raw, [2N,3N)=b_raw, [3N,4N)=c_raw
__global__ __launch_bounds__(256) void k_pass1(
    const unsigned short* __restrict__ P,
    const float* __restrict__ alog, const float* __restrict__ dbias,
    const float* __restrict__ pnb, const float* __restrict__ lgam,
    const float* __restrict__ sc,
    float* __restrict__ Asum, float* __restrict__ Ssum)
{
  const int tid = threadIdx.x;
  const int n0 = blockIdx.y*512 + tid*2;
  const int ch = blockIdx.x, b = blockIdx.z;
  const float ginv = __expf(lgam[0]) * sc[0];
  float alpha[2], bd[2], bb[2], bc[2], A[2], S[2];
  #pragma unroll
  for (int j = 0; j < 2; j++){
    alpha[j] = softplusf(alog[n0+j]);
    bd[j] = dbias[n0+j] + pnb[n0+j];
    bb[j] = pnb[N_ + n0+j];
    bc[j] = pnb[2*N_ + n0+j];
    A[j] = 1.f; S[j] = 0.f;
  }
  const unsigned short* Pr = P + (size_t)(b*T_ + ch*TC) * (4*N_);
  #pragma unroll 4
  for (int i = 0; i < TC; i++){
    unsigned int vp = *(const unsigned int*)(Pr + n0);
    unsigned int vd = *(const unsigned int*)(Pr + N_ + n0);
    unsigned int vb = *(const unsigned int*)(Pr + 2*N_ + n0);
    unsigned int vc = *(const unsigned int*)(Pr + 3*N_ + n0);
    #pragma unroll
    for (int j = 0; j < 2; j++){
      float pin  = bf2f((unsigned short)(j ? (vp>>16) : (vp & 0xffffu)));
      float draw = bf2f((unsigned short)(j ? (vd>>16) : (vd & 0xffffu))) + bd[j];
      float braw = bf2f((unsigned short)(j ? (vb>>16) : (vb & 0xffffu))) + bb[j];
      float craw = bf2f((unsigned short)(j ? (vc>>16) : (vc & 0xffffu))) + bc[j];
      float a, bu, c;
      abc_from(pin, draw, braw, craw, alpha[j], ginv, a, bu, c);
      S[j] = fmaf(a, S[j], bu);
      A[j] *= a;
    }
    Pr += 4*N_;
  }
  const size_t idx = (size_t)(b*NCH + ch)*N_ + n0;
  Asum[idx] = A[0]; Asum[idx+1] = A[1];
  Ssum[idx] = S[0]; Ssum[idx+1] = S[1];
}

__global__ void k_pass2(const float* __restrict__ Asum, const float* __restrict__ Ssum,
                        const float* __restrict__ z0, float* __restrict__ Zent)
{
  const int n = blockIdx.x*256 + threadIdx.x;
  const int b = blockIdx.y;
  float z = z0[b*N_ + n];
  for (int ch = 0; ch < NCH; ch++){
    const size_t idx = (size_t)(b*NCH + ch)*N_ + n;
    Zent[idx] = z;
    z = fmaf(Asum[idx], z, Ssum[idx]);
  }
}

__global__ __launch_bounds__(256) void k_pass3(
    const unsigned short* __restrict__ P,
    const float* __restrict__ alog, const float* __restrict__ dbias,
    const float* __restrict__ pnb, const float* __restrict__ lgam,
    const float* __restrict__ sc, const float* __restrict__ Zent,
    unsigned short* __restrict__ yh)
{
  const int tid = threadIdx.x;
  const int n0 = blockIdx.y*512 + tid*2;
  const int ch = blockIdx.x, b = blockIdx.z;
  const float ginv = __expf(lgam[0]) * sc[0];
  float alpha[2], bd[2], bb[2], bc[2], z[2];
  #pragma unroll
  for (int j = 0; j < 2; j++){
    alpha[j] = softplusf(alog[n0+j]);
    bd[j] = dbias[n0+j] + pnb[n0+j];
    bb[j] = pnb[N_ + n0+j];
    bc[j] = pnb[2*N_ + n0+j];
  }
  const size_t zidx = (size_t)(b*NCH + ch)*N_ + n0;
  z[0] = Zent[zidx]; z[1] = Zent[zidx+1];
  const unsigned short* Pr = P + (size_t)(b*T_ + ch*TC) * (4*N_);
  unsigned short* Y = yh + (size_t)(b*T_ + ch*TC)*N_ + n0;
  #pragma unroll 4
  for (int i = 0; i < TC; i++){
    unsigned int vp = *(const unsigned int*)(Pr + n0);
    unsigned int vd = *(const unsigned int*)(Pr + N_ + n0);
    unsigned int vb = *(const unsigned int*)(Pr + 2*N_ + n0);
    unsigned int vc = *(const unsigned int*)(Pr + 3*N_ + n0);
    unsigned int ow = 0;
    #pragma unroll
    for (int j = 0; j < 2; j++){
      float pin  = bf2f((unsigned short)(j ? (vp>>16) : (vp & 0xffffu)));
      float draw = bf2f((unsigned short)(j ? (vd>>16) : (vd & 0xffffu))) + bd[j];
      float braw = bf2f((unsigned short)(j ? (vb>>16) : (vb & 0xffffu))) + bb[j];
      float craw = bf2f((unsigned short)(j ? (vc>>16) : (vc & 0xffffu))) + bc[j];
      float a, bu, c;
      abc_from(pin, draw, braw, craw, alpha[j], ginv, a, bu, c);
      float yv = c * z[j];                 // state BEFORE update
      z[j] = fmaf(a, z[j], bu);
      ow |= ((unsigned int)f2bf(yv)) << (16*j);
    }
    *(unsigned int*)Y = ow;
    Y += N_;
    Pr += 4*N_;
  }
}

extern "C" void kernel_launch(void* const* d_in, const int* in_sizes, int n_in,
                              void* d_out, int out_size, void* d_ws, size_t ws_size,
                              hipStream_t stream)
{
  const float* u    = (const float*)d_in[0];
  const float* z0   = (const float*)d_in[1];
  const float* Win  = (const float*)d_in[2];
  const float* Wout = (const float*)d_in[3];
  const float* pnw  = (const float*)d_in[4];
  const float* pnb  = (const float*)d_in[5];
  const float* alog = (const float*)d_in[6];
  const float* dbias= (const float*)d_in[7];
  const float* lgam = (const float*)d_in[8];

  char* ws = (char*)d_ws;
  size_t off = 0;
  auto alloc = [&](size_t bytes) -> void* {
    void* p = ws + off;
    off += (bytes + 255) & ~(size_t)255;
    return p;
  };
  float*          sc     = (float*)         alloc(1024);
  unsigned short* u16    = (unsigned short*)alloc((size_t)8192*1024*2);
  unsigned short* Wcat16 = (unsigned short*)alloc((size_t)4096*1024*2);
  unsigned short* Wout16 = (unsigned short*)alloc((size_t)1024*1024*2);
  unsigned short* P16    = (unsigned short*)alloc((size_t)8192*4096*2);
  unsigned short* yh16   = (unsigned short*)alloc((size_t)8192*1024*2);
  unsigned short* Hping  = (unsigned short*)alloc((size_t)2*1024*1024*2);
  unsigned short* Hpong  = (unsigned short*)alloc((size_t)2*1024*1024*2);
  float*          Asum   = (float*)alloc((size_t)B_*NCH*N_*4);
  float*          Ssum   = (float*)alloc((size_t)B_*NCH*N_*4);
  float*          Zent   = (float*)alloc((size_t)B_*NCH*N_*4);

  k_init<<<1, 64, 0, stream>>>(sc);

  int n4;
  n4 = 8192*1024/4; k_convert<<<(n4+255)/256, 256, 0, stream>>>(u, u16, n4);
  n4 = 1024*1024/4; k_convert<<<(n4+255)/256, 256, 0, stream>>>(Win, Wcat16, n4);
  n4 = 3072*1024/4; k_convert<<<(n4+255)/256, 256, 0, stream>>>(pnw, Wcat16 + (size_t)1024*1024, n4);
  n4 = 1024*1024/4; k_convert<<<(n4+255)/256, 256, 0, stream>>>(Wout, Wout16, n4);

  // spectral-norm chains: gram (step 0) + KSQ trace-normalized squarings, both matrices in z
  dim3 gsq(8, 8, 2);
  k_gemm<1,1><<<gsq, 256, 0, stream>>>(Wcat16, nullptr, Hping, Wout16, Hping + (size_t)1024*1024,
                                       1024, 1024, 1024, sc, 0);
  unsigned short* hin = Hping;
  unsigned short* hout = Hpong;
  for (int s = 1; s <= KSQ; s++){
    k_gemm<1,1><<<gsq, 256, 0, stream>>>(hin, nullptr, hout, hin + (size_t)1024*1024,
                                         hout + (size_t)1024*1024, 1024, 1024, 1024, sc, s);
    unsigned short* t = hin; hin = hout; hout = t;
  }
  k_final<<<1, 64, 0, stream>>>(sc);

  // P = u @ [W_in; pn_w]^T  (bf16 out)
  dim3 g1(4096/128, 8192/128, 1);
  k_gemm<1,0><<<g1, 256, 0, stream>>>(u16, Wcat16, P16, nullptr, nullptr, 8192, 4096, 1024, sc, -1);

  dim3 gp1(NCH, N_/512, B_);
  k_pass1<<<gp1, 256, 0, stream>>>(P16, alog, dbias, pnb, lgam, sc, Asum, Ssum);
  dim3 gp2(N_/256, B_);
  k_pass2<<<gp2, 256, 0, stream>>>(Asum, Ssum, z0, Zent);
  k_pass3<<<gp1, 256, 0, stream>>>(P16, alog, dbias, pnb, lgam, sc, Zent, yh16);

  // y = (y_hat @ W_out^T) * inv_scale_out  (fp32 out)
  dim3 g2(1024/128, 8192/128, 1);
  k_gemm<0,0><<<g2, 256, 0, stream>>>(yh16, Wout16, d_out, nullptr, nullptr, 8192, 1024, 1024, sc, 1);
}

// Round 2
// 335.412 us; speedup vs baseline: 1.3478x; 1.3478x over previous
//
#include <hip/hip_runtime.h>
#include <stdint.h>

#define B_ 4
#define T_ 2048
#define D_ 1024
#define N_ 1024
#define TC 32
#define NCH (T_/TC)
#define SQN 8   // squaring GEMMs after gram; +1 effective doubling via Frobenius trace

typedef __attribute__((ext_vector_type(4))) float f32x4;
typedef __attribute__((ext_vector_type(8))) short bf16x8;
typedef __attribute__((ext_vector_type(4))) unsigned short us4;

__device__ __forceinline__ unsigned short f2bf(float f){
  unsigned int u = __float_as_uint(f);
  return (unsigned short)((u + 0x7fffu + ((u >> 16) & 1u)) >> 16);
}
__device__ __forceinline__ float bf2f(unsigned short h){
  return __uint_as_float(((unsigned int)h) << 16);
}

// ---- fused fp32->bf16 conversion of all inputs + sc zero-init ----
#define U4    2097152   // 8192*1024/4
#define WIN4   262144   // 1024*1024/4
#define PNW4   786432   // 3072*1024/4
#define WOUT4  262144
#define CONV_BLOCKS ((U4 + WIN4 + PNW4 + WOUT4 + 255)/256)

__global__ void k_convert_all(const float* __restrict__ u, const float* __restrict__ Win,
                              const float* __restrict__ pnw, const float* __restrict__ Wout,
                              unsigned short* __restrict__ u16, unsigned short* __restrict__ Wcat16,
                              unsigned short* __restrict__ Wout16, float* __restrict__ sc){
  if (blockIdx.x == 0 && threadIdx.x < 64) sc[threadIdx.x] = 0.f;
  long i = (long)blockIdx.x * 256 + threadIdx.x;   // float4 index
  const float* src; unsigned short* dst; long o;
  if (i < U4)                      { src = u;    dst = u16;             o = i; }
  else if (i < U4+WIN4)            { src = Win;  dst = Wcat16;          o = i - U4; }
  else if (i < U4+WIN4+PNW4)       { src = pnw;  dst = Wcat16 + 4194304/4*4 - 3145728; o = i - (U4+WIN4); } // Wcat16 + 1048576 elems
  else if (i < U4+WIN4+PNW4+WOUT4) { src = Wout; dst = Wout16;          o = i - (U4+WIN4+PNW4); }
  else return;
  float4 v = ((const float4*)src)[o];
  us4 w;
  w.x = f2bf(v.x); w.y = f2bf(v.y); w.z = f2bf(v.z); w.w = f2bf(v.w);
  ((us4*)dst)[o] = w;
}

__device__ __forceinline__ void load_lds16(const unsigned short* g, unsigned short* l){
  __builtin_amdgcn_global_load_lds((const __attribute__((address_space(1))) void*)g,
                                   (__attribute__((address_space(3))) void*)l, 16, 0, 0);
}

// ---- big GEMM: C[M,N] = (A[M,K] * B[N,K]^T) * (step>=0 ? sc[step] : 1)  (128x128 tile) ----
template<int OUTBF16>
__global__ __launch_bounds__(256) void k_gemm(
    const unsigned short* __restrict__ A,
    const unsigned short* __restrict__ Bmat,
    void* __restrict__ C0,
    int M, int N, int K,
    const float* __restrict__ sc, int step)
{
  __shared__ alignas(16) unsigned short As[128*64];
  __shared__ alignas(16) unsigned short Bs[128*64];
  const int tid = threadIdx.x;
  const int wid = tid >> 6;
  const int lane = tid & 63;

  // bijective XCD swizzle (nwg % 8 == 0 for both call sites)
  const int nwg = gridDim.x * gridDim.y;
  const int wgid = blockIdx.y * gridDim.x + blockIdx.x;
  const int swz = (wgid & 7) * (nwg >> 3) + (wgid >> 3);
  const int bn = swz % gridDim.x, bm = swz / gridDim.x;

  char* C = (char*)C0;
  float outscale = (step >= 0) ? sc[step] : 1.f;

  const int wr = wid >> 1, wc = wid & 1;
  const int rg = lane >> 3;
  const int cby = (lane & 7) << 4;
  const int srow0 = wid * 32;
  const int frow = lane & 15;
  const int kgrp = lane >> 4;

  const size_t Abase = (size_t)bm * 128 * K;
  const size_t Bbase = (size_t)bn * 128 * K;

  f32x4 acc[4][4] = {};

  for (int kt = 0; kt < K; kt += 64){
    #pragma unroll
    for (int i = 0; i < 4; i++){
      int r = srow0 + i*8 + rg;
      int cb = cby ^ ((r & 7) << 4);
      load_lds16(A    + Abase + (size_t)r*K + kt + (cb >> 1), As + (srow0 + i*8)*64);
      load_lds16(Bmat + Bbase + (size_t)r*K + kt + (cb >> 1), Bs + (srow0 + i*8)*64);
    }
    __syncthreads();
    #pragma unroll
    for (int kk = 0; kk < 2; kk++){
      const int kbyte = kk*64 + kgrp*16;
      bf16x8 af[4], bfv[4];
      #pragma unroll
      for (int m = 0; m < 4; m++){
        int r = wr*64 + m*16 + frow;
        af[m] = *(const bf16x8*)((const char*)As + r*128 + (kbyte ^ ((r & 7) << 4)));
      }
      #pragma unroll
      for (int n2 = 0; n2 < 4; n2++){
        int r = wc*64 + n2*16 + frow;
        bfv[n2] = *(const bf16x8*)((const char*)Bs + r*128 + (kbyte ^ ((r & 7) << 4)));
      }
      #pragma unroll
      for (int m = 0; m < 4; m++)
        #pragma unroll
        for (int n2 = 0; n2 < 4; n2++)
          acc[m][n2] = __builtin_amdgcn_mfma_f32_16x16x32_bf16(af[m], bfv[n2], acc[m][n2], 0, 0, 0);
    }
    __syncthreads();
  }

  const int row0 = bm*128 + wr*64;
  const int col0 = bn*128 + wc*64 + frow;
  #pragma unroll
  for (int m = 0; m < 4; m++){
    #pragma unroll
    for (int n2 = 0; n2 < 4; n2++){
      const int col = col0 + n2*16;
      const int rb = row0 + m*16 + kgrp*4;
      #pragma unroll
      for (int j = 0; j < 4; j++){
        float v = acc[m][n2][j] * outscale;
        if (OUTBF16) ((unsigned short*)C)[(size_t)(rb + j)*N + col] = f2bf(v);
        else         ((float*)C)[(size_t)(rb + j)*N + col] = v;
      }
    }
  }
}

// ---- squaring-chain GEMM: 64x64 tile, C = (A/t)^2 for symmetric A (two chains in z) ----
// step 0: C = A*A^T (gram), scale 1. step>0: scale = 1/t_{step-1}^2.
// trace of scaled output accumulated into sc[8+2*step+z].
__global__ __launch_bounds__(256) void k_sq(
    const unsigned short* __restrict__ A0, unsigned short* __restrict__ C0,
    const unsigned short* __restrict__ A1, unsigned short* __restrict__ C1,
    float* __restrict__ sc, int step)
{
  __shared__ alignas(16) unsigned short As[64*64];
  __shared__ alignas(16) unsigned short Bs[64*64];
  const int tid = threadIdx.x;
  const int wid = tid >> 6;
  const int lane = tid & 63;
  const int bn = blockIdx.x, bm = blockIdx.y, z = blockIdx.z;

  const unsigned short* A = z ? A1 : A0;
  unsigned short* C = z ? C1 : C0;
  float outscale = 1.f;
  if (step > 0){ float t = sc[8 + (step-1)*2 + z]; outscale = 1.f/(t*t); }

  const int wr = wid >> 1, wc = wid & 1;     // 32x32 quadrant per wave
  const int rg = lane >> 3;
  const int cby = (lane & 7) << 4;
  const int frow = lane & 15;
  const int kgrp = lane >> 4;

  f32x4 acc[2][2] = {};

  for (int kt = 0; kt < 1024; kt += 64){
    #pragma unroll
    for (int i = 0; i < 2; i++){
      int rr = i*32 + wid*8 + rg;
      int cb = cby ^ ((rr & 7) << 4);
      load_lds16(A + (size_t)(bm*64 + rr)*1024 + kt + (cb >> 1), As + (i*32 + wid*8)*64);
      load_lds16(A + (size_t)(bn*64 + rr)*1024 + kt + (cb >> 1), Bs + (i*32 + wid*8)*64);
    }
    __syncthreads();
    #pragma unroll
    for (int kk = 0; kk < 2; kk++){
      const int kbyte = kk*64 + kgrp*16;
      bf16x8 af[2], bfv[2];
      #pragma unroll
      for (int m = 0; m < 2; m++){
        int r = wr*32 + m*16 + frow;
        af[m] = *(const bf16x8*)((const char*)As + r*128 + (kbyte ^ ((r & 7) << 4)));
      }
      #pragma unroll
      for (int n2 = 0; n2 < 2; n2++){
        int r = wc*32 + n2*16 + frow;
        bfv[n2] = *(const bf16x8*)((const char*)Bs + r*128 + (kbyte ^ ((r & 7) << 4)));
      }
      #pragma unroll
      for (int m = 0; m < 2; m++)
        #pragma unroll
        for (int n2 = 0; n2 < 2; n2++)
          acc[m][n2] = __builtin_amdgcn_mfma_f32_16x16x32_bf16(af[m], bfv[n2], acc[m][n2], 0, 0, 0);
    }
    __syncthreads();
  }

  const int row0 = bm*64 + wr*32;
  const int col0 = bn*64 + wc*32 + frow;
  #pragma unroll
  for (int m = 0; m < 2; m++){
    #pragma unroll
    for (int n2 = 0; n2 < 2; n2++){
      const int col = col0 + n2*16;
      const int rb = row0 + m*16 + kgrp*4;
      #pragma unroll
      for (int j = 0; j < 4; j++)
        C[(size_t)(rb + j)*1024 + col] = f2bf(acc[m][n2][j] * outscale);
    }
  }
  if (bm == bn && wr == wc){
    int j = frow - kgrp*4;
    if (j >= 0 && j < 4){
      float d = (acc[0][0][j] + acc[1][1][j]) * outscale;
      atomicAdd(&sc[8 + step*2 + z], d);
    }
  }
}

// ---- Frobenius: sc[8+2*(SQN+1)+z] = ||H_z||_F^2  (equals tr(H^2), one free doubling) ----
__global__ __launch_bounds__(256) void k_frob(const unsigned short* __restrict__ H0,
                                              const unsigned short* __restrict__ H1,
                                              float* __restrict__ sc){
  const unsigned short* H = blockIdx.y ? H1 : H0;
  __shared__ float red[4];
  const int tid = threadIdx.x;
  float s = 0.f;
  #pragma unroll
  for (int k = 0; k < 8; k++){
    us4 v = ((const us4*)H)[(size_t)blockIdx.x*2048 + k*256 + tid];
    float a = bf2f(v.x), b = bf2f(v.y), c = bf2f(v.z), d = bf2f(v.w);
    s += a*a + b*b + c*c + d*d;
  }
  #pragma unroll
  for (int off = 32; off; off >>= 1) s += __shfl_down(s, off, 64);
  if ((tid & 63) == 0) red[tid >> 6] = s;
  __syncthreads();
  if (tid == 0) atomicAdd(&sc[8 + 2*(SQN+1) + blockIdx.y], red[0]+red[1]+red[2]+red[3]);
}

__global__ void k_final(float* sc){
  int z = threadIdx.x;
  if (z < 2){
    float ll = 0.f, w = 1.f, t = 1.f;
    for (int i = 0; i <= SQN; i++){
      t = sc[8 + 2*i + z];
      ll += w * __logf(t);
      w *= 0.5f;
    }
    float tlast = sc[8 + 2*(SQN+1) + z] / (t*t);
    ll += w * __logf(tlast);
    float sig = __expf(0.5f * ll);
    sig = fmaxf(sig, 1e-5f);
    sc[z] = 1.f / fmaxf(sig, 1.f);
  }
}

__device__ __forceinline__ float softplusf(float x){
  return (x > 0.f) ? (x + __logf(1.f + __expf(-x))) : __logf(1.f + __expf(x));
}
__device__ __forceinline__ float tanhfastf(float x){
  float e = __expf(2.f * x);
  return 1.f - 2.f/(e + 1.f);
}
__device__ __forceinline__ void abc_from(float pin, float draw, float braw, float craw,
    float alpha, float ginv, float& a_o, float& bu_o, float& c_o){
  float sp = softplusf(draw);
  float av = __expf(-sp * alpha);
  av = fminf(av, 1.f - 1e-4f);
  float bv = tanhfastf(braw);
  float cv = tanhfastf(craw);
  float p = av*av + cv*cv;
  float r = bv*bv;
  float q = av*bv;
  float pr = p - r;
  float disc = pr*pr + 4.f*q*q;
  float lam = 0.5f*(p + r + sqrtf(disc + 1e-12f));
  float sig = sqrtf(lam + 1e-12f);
  float inv = 1.f / fmaxf(sig, 1.f);
  a_o = av * inv;
  c_o = cv * inv;
  bu_o = (bv * inv) * (pin * ginv);
}

__global__ __launch_bounds__(256) void k_pass1(
    const unsigned short* __restrict__ P,
    const float* __restrict__ alog, const float* __restrict__ dbias,
    const float* __restrict__ pnb, const float* __restrict__ lgam,
    const float* __restrict__ sc,
    float* __restrict__ Asum, float* __restrict__ Ssum)
{
  const int tid = threadIdx.x;
  const int n0 = blockIdx.y*512 + tid*2;
  const int ch = blockIdx.x, b = blockIdx.z;
  const float ginv = __expf(lgam[0]) * sc[0];
  float alpha[2], bd[2], bb[2], bc[2], A[2], S[2];
  #pragma unroll
  for (int j = 0; j < 2; j++){
    alpha[j] = softplusf(alog[n0+j]);
    bd[j] = dbias[n0+j] + pnb[n0+j];
    bb[j] = pnb[N_ + n0+j];
    bc[j] = pnb[2*N_ + n0+j];
    A[j] = 1.f; S[j] = 0.f;
  }
  const unsigned short* Pr = P + (size_t)(b*T_ + ch*TC) * (4*N_);
  #pragma unroll 4
  for (int i = 0; i < TC; i++){
    unsigned int vp = *(const unsigned int*)(Pr + n0);
    unsigned int vd = *(const unsigned int*)(Pr + N_ + n0);
    unsigned int vb = *(const unsigned int*)(Pr + 2*N_ + n0);
    unsigned int vc = *(const unsigned int*)(Pr + 3*N_ + n0);
    #pragma unroll
    for (int j = 0; j < 2; j++){
      float pin  = bf2f((unsigned short)(j ? (vp>>16) : (vp & 0xffffu)));
      float draw = bf2f((unsigned short)(j ? (vd>>16) : (vd & 0xffffu))) + bd[j];
      float braw = bf2f((unsigned short)(j ? (vb>>16) : (vb & 0xffffu))) + bb[j];
      float craw = bf2f((unsigned short)(j ? (vc>>16) : (vc & 0xffffu))) + bc[j];
      float a, bu, c;
      abc_from(pin, draw, braw, craw, alpha[j], ginv, a, bu, c);
      S[j] = fmaf(a, S[j], bu);
      A[j] *= a;
    }
    Pr += 4*N_;
  }
  const size_t idx = (size_t)(b*NCH + ch)*N_ + n0;
  Asum[idx] = A[0]; Asum[idx+1] = A[1];
  Ssum[idx] = S[0]; Ssum[idx+1] = S[1];
}

__global__ void k_pass2(const float* __restrict__ Asum, const float* __restrict__ Ssum,
                        const float* __restrict__ z0, float* __restrict__ Zent)
{
  const int n = blockIdx.x*256 + threadIdx.x;
  const int b = blockIdx.y;
  float z = z0[b*N_ + n];
  for (int ch = 0; ch < NCH; ch++){
    const size_t idx = (size_t)(b*NCH + ch)*N_ + n;
    Zent[idx] = z;
    z = fmaf(Asum[idx], z, Ssum[idx]);
  }
}

__global__ __launch_bounds__(256) void k_pass3(
    const unsigned short* __restrict__ P,
    const float* __restrict__ alog, const float* __restrict__ dbias,
    const float* __restrict__ pnb, const float* __restrict__ lgam,
    const float* __restrict__ sc, const float* __restrict__ Zent,
    unsigned short* __restrict__ yh)
{
  const int tid = threadIdx.x;
  const int n0 = blockIdx.y*512 + tid*2;
  const int ch = blockIdx.x, b = blockIdx.z;
  const float ginv = __expf(lgam[0]) * sc[0];
  float alpha[2], bd[2], bb[2], bc[2], z[2];
  #pragma unroll
  for (int j = 0; j < 2; j++){
    alpha[j] = softplusf(alog[n0+j]);
    bd[j] = dbias[n0+j] + pnb[n0+j];
    bb[j] = pnb[N_ + n0+j];
    bc[j] = pnb[2*N_ + n0+j];
  }
  const size_t zidx = (size_t)(b*NCH + ch)*N_ + n0;
  z[0] = Zent[zidx]; z[1] = Zent[zidx+1];
  const unsigned short* Pr = P + (size_t)(b*T_ + ch*TC) * (4*N_);
  unsigned short* Y = yh + (size_t)(b*T_ + ch*TC)*N_ + n0;
  #pragma unroll 4
  for (int i = 0; i < TC; i++){
    unsigned int vp = *(const unsigned int*)(Pr + n0);
    unsigned int vd = *(const unsigned int*)(Pr + N_ + n0);
    unsigned int vb = *(const unsigned int*)(Pr + 2*N_ + n0);
    unsigned int vc = *(const unsigned int*)(Pr + 3*N_ + n0);
    unsigned int ow = 0;
    #pragma unroll
    for (int j = 0; j < 2; j++){
      float pin  = bf2f((unsigned short)(j ? (vp>>16) : (vp & 0xffffu)));
      float draw = bf2f((unsigned short)(j ? (vd>>16) : (vd & 0xffffu))) + bd[j];
      float braw = bf2f((unsigned short)(j ? (vb>>16) : (vb & 0xffffu))) + bb[j];
      float craw = bf2f((unsigned short)(j ? (vc>>16) : (vc & 0xffffu))) + bc[j];
      float a, bu, c;
      abc_from(pin, draw, braw, craw, alpha[j], ginv, a, bu, c);
      float yv = c * z[j];
      z[j] = fmaf(a, z[j], bu);
      ow |= ((unsigned int)f2bf(yv)) << (16*j);
    }
    *(unsigned int*)Y = ow;
    Y += N_;
    Pr += 4*N_;
  }
}

extern "C" void kernel_launch(void* const* d_in, const int* in_sizes, int n_in,
                              void* d_out, int out_size, void* d_ws, size_t ws_size,
                              hipStream_t stream)
{
  const float* u    = (const float*)d_in[0];
  const float* z0   = (const float*)d_in[1];
  const float* Win  = (const float*)d_in[2];
  const float* Wout = (const float*)d_in[3];
  const float* pnw  = (const float*)d_in[4];
  const float* pnb  = (const float*)d_in[5];
  const float* alog = (const float*)d_in[6];
  const float* dbias= (const float*)d_in[7];
  const float* lgam = (const float*)d_in[8];

  char* ws = (char*)d_ws;
  size_t off = 0;
  auto alloc = [&](size_t bytes) -> void* {
    void* p = ws + off;
    off += (bytes + 255) & ~(size_t)255;
    return p;
  };
  float*          sc     = (float*)         alloc(1024);
  unsigned short* u16    = (unsigned short*)alloc((size_t)8192*1024*2);
  unsigned short* Wcat16 = (unsigned short*)alloc((size_t)4096*1024*2);
  unsigned short* Wout16 = (unsigned short*)alloc((size_t)1024*1024*2);
  unsigned short* P16    = (unsigned short*)alloc((size_t)8192*4096*2);
  unsigned short* yh16   = (unsigned short*)alloc((size_t)8192*1024*2);
  unsigned short* Hping  = (unsigned short*)alloc((size_t)2*1024*1024*2);
  unsigned short* Hpong  = (unsigned short*)alloc((size_t)2*1024*1024*2);
  float*          Asum   = (float*)alloc((size_t)B_*NCH*N_*4);
  float*          Ssum   = (float*)alloc((size_t)B_*NCH*N_*4);
  float*          Zent   = (float*)alloc((size_t)B_*NCH*N_*4);

  k_convert_all<<<CONV_BLOCKS, 256, 0, stream>>>(u, Win, pnw, Wout, u16, Wcat16, Wout16, sc);

  // spectral-norm chains: gram (step 0) + SQN trace-normalized squarings + Frobenius doubling
  dim3 gsq(16, 16, 2);
  k_sq<<<gsq, 256, 0, stream>>>(Wcat16, Hping, Wout16, Hping + (size_t)1024*1024, sc, 0);
  unsigned short* hin = Hping;
  unsigned short* hout = Hpong;
  for (int s = 1; s <= SQN; s++){
    k_sq<<<gsq, 256, 0, stream>>>(hin, hout, hin + (size_t)1024*1024, hout + (size_t)1024*1024, sc, s);
    unsigned short* t = hin; hin = hout; hout = t;
  }
  dim3 gfr(128, 2);
  k_frob<<<gfr, 256, 0, stream>>>(hin, hin + (size_t)1024*1024, sc);
  k_final<<<1, 64, 0, stream>>>(sc);

  // P = u @ [W_in; pn_w]^T  (bf16 out, no scale — sc[0] applied in pass1/pass3)
  dim3 g1(4096/128, 8192/128, 1);
  k_gemm<1><<<g1, 256, 0, stream>>>(u16, Wcat16, P16, 8192, 4096, 1024, sc, -1);

  dim3 gp1(NCH, N_/512, B_);
  k_pass1<<<gp1, 256, 0, stream>>>(P16, alog, dbias, pnb, lgam, sc, Asum, Ssum);
  dim3 gp2(N_/256, B_);
  k_pass2<<<gp2, 256, 0, stream>>>(Asum, Ssum, z0, Zent);
  k_pass3<<<gp1, 256, 0, stream>>>(P16, alog, dbias, pnb, lgam, sc, Zent, yh16);

  // y = (y_hat @ W_out^T) * sc[1]  (fp32 out)
  dim3 g2(1024/128, 8192/128, 1);
  k_gemm<0><<<g2, 256, 0, stream>>>(yh16, Wout16, d_out, 8192, 1024, 1024, sc, 1);
}

// Round 3
// 320.945 us; speedup vs baseline: 1.4086x; 1.0451x over previous
//
#include <hip/hip_runtime.h>
#include <stdint.h>

#define B_ 4
#define T_ 2048
#define D_ 1024
#define N_ 1024
#define TC 32
#define NCH (T_/TC)
#define SQN 8   // squaring GEMMs after gram; +1 effective doubling via fused Frobenius

typedef __attribute__((ext_vector_type(4))) float f32x4;
typedef __attribute__((ext_vector_type(8))) short bf16x8;
typedef __attribute__((ext_vector_type(4))) unsigned short us4;

__device__ __forceinline__ unsigned short f2bf(float f){
  unsigned int u = __float_as_uint(f);
  return (unsigned short)((u + 0x7fffu + ((u >> 16) & 1u)) >> 16);
}
__device__ __forceinline__ float bf2f(unsigned short h){
  return __uint_as_float(((unsigned int)h) << 16);
}

// ---- fused fp32->bf16 conversion of all inputs + sc zero-init ----
#define U4    2097152   // 8192*1024/4
#define WIN4   262144   // 1024*1024/4
#define PNW4   786432   // 3072*1024/4
#define WOUT4  262144
#define CONV_BLOCKS ((U4 + WIN4 + PNW4 + WOUT4 + 255)/256)

__global__ void k_convert_all(const float* __restrict__ u, const float* __restrict__ Win,
                              const float* __restrict__ pnw, const float* __restrict__ Wout,
                              unsigned short* __restrict__ u16, unsigned short* __restrict__ Wcat16,
                              unsigned short* __restrict__ Wout16, float* __restrict__ sc){
  if (blockIdx.x == 0 && threadIdx.x < 64) sc[threadIdx.x] = 0.f;
  long i = (long)blockIdx.x * 256 + threadIdx.x;   // float4 index
  const float* src; unsigned short* dst; long o;
  if (i < U4)                      { src = u;    dst = u16;               o = i; }
  else if (i < U4+WIN4)            { src = Win;  dst = Wcat16;            o = i - U4; }
  else if (i < U4+WIN4+PNW4)       { src = pnw;  dst = Wcat16 + 1048576;  o = i - (U4+WIN4); }
  else if (i < U4+WIN4+PNW4+WOUT4) { src = Wout; dst = Wout16;            o = i - (U4+WIN4+PNW4); }
  else return;
  float4 v = ((const float4*)src)[o];
  us4 w;
  w.x = f2bf(v.x); w.y = f2bf(v.y); w.z = f2bf(v.z); w.w = f2bf(v.w);
  ((us4*)dst)[o] = w;
}

__device__ __forceinline__ void load_lds16(const unsigned short* g, unsigned short* l){
  __builtin_amdgcn_global_load_lds((const __attribute__((address_space(1))) void*)g,
                                   (__attribute__((address_space(3))) void*)l, 16, 0, 0);
}

// ---- big GEMM: C[M,N] = (A[M,K] * B[N,K]^T) * (step>=0 ? sc[step] : 1)  (128x128 tile) ----
// No XCD swizzle: default round-robin dispatch gives better L2 partitioning here (R2 post-mortem).
template<int OUTBF16>
__global__ __launch_bounds__(256) void k_gemm(
    const unsigned short* __restrict__ A,
    const unsigned short* __restrict__ Bmat,
    void* __restrict__ C0,
    int M, int N, int K,
    const float* __restrict__ sc, int step)
{
  __shared__ alignas(16) unsigned short As[128*64];
  __shared__ alignas(16) unsigned short Bs[128*64];
  const int tid = threadIdx.x;
  const int wid = tid >> 6;
  const int lane = tid & 63;
  const int bn = blockIdx.x, bm = blockIdx.y;

  char* C = (char*)C0;
  float outscale = (step >= 0) ? sc[step] : 1.f;

  const int wr = wid >> 1, wc = wid & 1;
  const int rg = lane >> 3;
  const int cby = (lane & 7) << 4;
  const int srow0 = wid * 32;
  const int frow = lane & 15;
  const int kgrp = lane >> 4;

  const size_t Abase = (size_t)bm * 128 * K;
  const size_t Bbase = (size_t)bn * 128 * K;

  f32x4 acc[4][4] = {};

  for (int kt = 0; kt < K; kt += 64){
    #pragma unroll
    for (int i = 0; i < 4; i++){
      int r = srow0 + i*8 + rg;
      int cb = cby ^ ((r & 7) << 4);
      load_lds16(A    + Abase + (size_t)r*K + kt + (cb >> 1), As + (srow0 + i*8)*64);
      load_lds16(Bmat + Bbase + (size_t)r*K + kt + (cb >> 1), Bs + (srow0 + i*8)*64);
    }
    __syncthreads();
    #pragma unroll
    for (int kk = 0; kk < 2; kk++){
      const int kbyte = kk*64 + kgrp*16;
      bf16x8 af[4], bfv[4];
      #pragma unroll
      for (int m = 0; m < 4; m++){
        int r = wr*64 + m*16 + frow;
        af[m] = *(const bf16x8*)((const char*)As + r*128 + (kbyte ^ ((r & 7) << 4)));
      }
      #pragma unroll
      for (int n2 = 0; n2 < 4; n2++){
        int r = wc*64 + n2*16 + frow;
        bfv[n2] = *(const bf16x8*)((const char*)Bs + r*128 + (kbyte ^ ((r & 7) << 4)));
      }
      #pragma unroll
      for (int m = 0; m < 4; m++)
        #pragma unroll
        for (int n2 = 0; n2 < 4; n2++)
          acc[m][n2] = __builtin_amdgcn_mfma_f32_16x16x32_bf16(af[m], bfv[n2], acc[m][n2], 0, 0, 0);
    }
    __syncthreads();
  }

  const int row0 = bm*128 + wr*64;
  const int col0 = bn*128 + wc*64 + frow;
  #pragma unroll
  for (int m = 0; m < 4; m++){
    #pragma unroll
    for (int n2 = 0; n2 < 4; n2++){
      const int col = col0 + n2*16;
      const int rb = row0 + m*16 + kgrp*4;
      #pragma unroll
      for (int j = 0; j < 4; j++){
        float v = acc[m][n2][j] * outscale;
        if (OUTBF16) ((unsigned short*)C)[(size_t)(rb + j)*N + col] = f2bf(v);
        else         ((float*)C)[(size_t)(rb + j)*N + col] = v;
      }
    }
  }
}

// ---- squaring-chain GEMM: 64x64 tile, BK=128, double-buffered 2-phase prefetch ----
// step 0: C = A*A^T (gram). step>0: C = (A/t)^2. Trace of stored C -> sc[8+2*step+z].
// step==SQN additionally accumulates ||C||_F^2 -> sc[8+2*(SQN+1)+z] (free extra doubling).
__global__ __launch_bounds__(256) void k_sq(
    const unsigned short* __restrict__ A0, unsigned short* __restrict__ C0,
    const unsigned short* __restrict__ A1, unsigned short* __restrict__ C1,
    float* __restrict__ sc, int step)
{
  __shared__ alignas(16) unsigned short As0[64*128], Bs0[64*128];
  __shared__ alignas(16) unsigned short As1[64*128], Bs1[64*128];
  const int tid = threadIdx.x;
  const int wid = tid >> 6;
  const int lane = tid & 63;
  const int bn = blockIdx.x, bm = blockIdx.y, z = blockIdx.z;

  const unsigned short* A = z ? A1 : A0;
  unsigned short* C = z ? C1 : C0;
  float outscale = 1.f;
  if (step > 0){ float t = sc[8 + (step-1)*2 + z]; outscale = 1.f/(t*t); }

  const int wr = wid >> 1, wc = wid & 1;     // 32x32 quadrant per wave
  const int frow = lane & 15;
  const int kgrp = lane >> 4;

  // staging: wave w stages rows {i*16 + w*4 .. +3}; lane -> (row=lane>>4, granule=lane&15)
  const int srl = lane >> 4;                 // 0..3
  const int sgr = lane & 15;                 // 16B granule within 256B row
  const int swzr = wid*4 + srl;              // == (row & 15) for staged rows
  const int scol_e = ((sgr ^ swzr) << 3);    // pre-swizzled element col (16B = 8 elems)

  const size_t Arow = (size_t)bm * 64;
  const size_t Brow = (size_t)bn * 64;

  f32x4 acc[2][2] = {};

  auto stage = [&](unsigned short* as, unsigned short* bs, int t){
    const int kt = t * 128;
    #pragma unroll
    for (int i = 0; i < 4; i++){
      int r = i*16 + wid*4 + srl;
      load_lds16(A + (Arow + r)*1024 + kt + scol_e, as + (i*16 + wid*4)*128);
      load_lds16(A + (Brow + r)*1024 + kt + scol_e, bs + (i*16 + wid*4)*128);
    }
  };

  auto compute = [&](const unsigned short* as, const unsigned short* bs){
    #pragma unroll
    for (int ks = 0; ks < 4; ks++){
      const int kb = ks*64 + kgrp*16;
      bf16x8 af[2], bfv[2];
      #pragma unroll
      for (int m = 0; m < 2; m++){
        int r = wr*32 + m*16 + frow;
        af[m] = *(const bf16x8*)((const char*)as + r*256 + (kb ^ (frow << 4)));
      }
      #pragma unroll
      for (int n2 = 0; n2 < 2; n2++){
        int r = wc*32 + n2*16 + frow;
        bfv[n2] = *(const bf16x8*)((const char*)bs + r*256 + (kb ^ (frow << 4)));
      }
      #pragma unroll
      for (int m = 0; m < 2; m++)
        #pragma unroll
        for (int n2 = 0; n2 < 2; n2++)
          acc[m][n2] = __builtin_amdgcn_mfma_f32_16x16x32_bf16(af[m], bfv[n2], acc[m][n2], 0, 0, 0);
    }
  };

  stage(As0, Bs0, 0);
  __syncthreads();                        // vmcnt(0)+barrier: buf0 ready
  for (int t2 = 0; t2 < 8; t2 += 2){
    if (t2 + 1 < 8) stage(As1, Bs1, t2 + 1);   // prefetch next tile
    compute(As0, Bs0);
    __syncthreads();                           // drains vmcnt(0): buf1 ready
    if (t2 + 2 < 8) stage(As0, Bs0, t2 + 2);
    compute(As1, Bs1);
    __syncthreads();
  }

  const int row0 = bm*64 + wr*32;
  const int col0 = bn*64 + wc*32 + frow;
  float fr = 0.f;
  #pragma unroll
  for (int m = 0; m < 2; m++){
    #pragma unroll
    for (int n2 = 0; n2 < 2; n2++){
      const int col = col0 + n2*16;
      const int rb = row0 + m*16 + kgrp*4;
      #pragma unroll
      for (int j = 0; j < 4; j++){
        float v = acc[m][n2][j] * outscale;
        C[(size_t)(rb + j)*1024 + col] = f2bf(v);
        fr += v*v;
      }
    }
  }
  if (bm == bn && wr == wc){
    int j = frow - kgrp*4;
    if (j >= 0 && j < 4){
      float d = (acc[0][0][j] + acc[1][1][j]) * outscale;
      atomicAdd(&sc[8 + step*2 + z], d);
    }
  }
  if (step == SQN){
    #pragma unroll
    for (int off = 32; off; off >>= 1) fr += __shfl_down(fr, off, 64);
    if (lane == 0) atomicAdd(&sc[8 + 2*(SQN+1) + z], fr);
  }
}

__global__ void k_final(float* sc){
  int z = threadIdx.x;
  if (z < 2){
    float ll = 0.f, w = 1.f, t = 1.f;
    for (int i = 0; i <= SQN; i++){
      t = sc[8 + 2*i + z];
      ll += w * __logf(t);
      w *= 0.5f;
    }
    float tlast = sc[8 + 2*(SQN+1) + z] / (t*t);
    ll += w * __logf(tlast);
    float sig = __expf(0.5f * ll);
    sig = fmaxf(sig, 1e-5f);
    sc[z] = 1.f / fmaxf(sig, 1.f);
  }
}

__device__ __forceinline__ float softplusf(float x){
  return (x > 0.f) ? (x + __logf(1.f + __expf(-x))) : __logf(1.f + __expf(x));
}
__device__ __forceinline__ float tanhfastf(float x){
  float e = __expf(2.f * x);
  return 1.f - 2.f/(e + 1.f);
}
__device__ __forceinline__ void abc_from(float pin, float draw, float braw, float craw,
    float alpha, float ginv, float& a_o, float& bu_o, float& c_o){
  float sp = softplusf(draw);
  float av = __expf(-sp * alpha);
  av = fminf(av, 1.f - 1e-4f);
  float bv = tanhfastf(braw);
  float cv = tanhfastf(craw);
  float p = av*av + cv*cv;
  float r = bv*bv;
  float q = av*bv;
  float pr = p - r;
  float disc = pr*pr + 4.f*q*q;
  float lam = 0.5f*(p + r + sqrtf(disc + 1e-12f));
  float sig = sqrtf(lam + 1e-12f);
  float inv = 1.f / fmaxf(sig, 1.f);
  a_o = av * inv;
  c_o = cv * inv;
  bu_o = (bv * inv) * (pin * ginv);
}

__global__ __launch_bounds__(256) void k_pass1(
    const unsigned short* __restrict__ P,
    const float* __restrict__ alog, const float* __restrict__ dbias,
    const float* __restrict__ pnb, const float* __restrict__ lgam,
    const float* __restrict__ sc,
    float* __restrict__ Asum, float* __restrict__ Ssum)
{
  const int tid = threadIdx.x;
  const int n0 = blockIdx.y*512 + tid*2;
  const int ch = blockIdx.x, b = blockIdx.z;
  const float ginv = __expf(lgam[0]) * sc[0];
  float alpha[2], bd[2], bb[2], bc[2], A[2], S[2];
  #pragma unroll
  for (int j = 0; j < 2; j++){
    alpha[j] = softplusf(alog[n0+j]);
    bd[j] = dbias[n0+j] + pnb[n0+j];
    bb[j] = pnb[N_ + n0+j];
    bc[j] = pnb[2*N_ + n0+j];
    A[j] = 1.f; S[j] = 0.f;
  }
  const unsigned short* Pr = P + (size_t)(b*T_ + ch*TC) * (4*N_);
  #pragma unroll 4
  for (int i = 0; i < TC; i++){
    unsigned int vp = *(const unsigned int*)(Pr + n0);
    unsigned int vd = *(const unsigned int*)(Pr + N_ + n0);
    unsigned int vb = *(const unsigned int*)(Pr + 2*N_ + n0);
    unsigned int vc = *(const unsigned int*)(Pr + 3*N_ + n0);
    #pragma unroll
    for (int j = 0; j < 2; j++){
      float pin  = bf2f((unsigned short)(j ? (vp>>16) : (vp & 0xffffu)));
      float draw = bf2f((unsigned short)(j ? (vd>>16) : (vd & 0xffffu))) + bd[j];
      float braw = bf2f((unsigned short)(j ? (vb>>16) : (vb & 0xffffu))) + bb[j];
      float craw = bf2f((unsigned short)(j ? (vc>>16) : (vc & 0xffffu))) + bc[j];
      float a, bu, c;
      abc_from(pin, draw, braw, craw, alpha[j], ginv, a, bu, c);
      S[j] = fmaf(a, S[j], bu);
      A[j] *= a;
    }
    Pr += 4*N_;
  }
  const size_t idx = (size_t)(b*NCH + ch)*N_ + n0;
  Asum[idx] = A[0]; Asum[idx+1] = A[1];
  Ssum[idx] = S[0]; Ssum[idx+1] = S[1];
}

__global__ void k_pass2(const float* __restrict__ Asum, const float* __restrict__ Ssum,
                        const float* __restrict__ z0, float* __restrict__ Zent)
{
  const int n = blockIdx.x*256 + threadIdx.x;
  const int b = blockIdx.y;
  float z = z0[b*N_ + n];
  for (int ch = 0; ch < NCH; ch++){
    const size_t idx = (size_t)(b*NCH + ch)*N_ + n;
    Zent[idx] = z;
    z = fmaf(Asum[idx], z, Ssum[idx]);
  }
}

__global__ __launch_bounds__(256) void k_pass3(
    const unsigned short* __restrict__ P,
    const float* __restrict__ alog, const float* __restrict__ dbias,
    const float* __restrict__ pnb, const float* __restrict__ lgam,
    const float* __restrict__ sc, const float* __restrict__ Zent,
    unsigned short* __restrict__ yh)
{
  const int tid = threadIdx.x;
  const int n0 = blockIdx.y*512 + tid*2;
  const int ch = blockIdx.x, b = blockIdx.z;
  const float ginv = __expf(lgam[0]) * sc[0];
  float alpha[2], bd[2], bb[2], bc[2], z[2];
  #pragma unroll
  for (int j = 0; j < 2; j++){
    alpha[j] = softplusf(alog[n0+j]);
    bd[j] = dbias[n0+j] + pnb[n0+j];
    bb[j] = pnb[N_ + n0+j];
    bc[j] = pnb[2*N_ + n0+j];
  }
  const size_t zidx = (size_t)(b*NCH + ch)*N_ + n0;
  z[0] = Zent[zidx]; z[1] = Zent[zidx+1];
  const unsigned short* Pr = P + (size_t)(b*T_ + ch*TC) * (4*N_);
  unsigned short* Y = yh + (size_t)(b*T_ + ch*TC)*N_ + n0;
  #pragma unroll 4
  for (int i = 0; i < TC; i++){
    unsigned int vp = *(const unsigned int*)(Pr + n0);
    unsigned int vd = *(const unsigned int*)(Pr + N_ + n0);
    unsigned int vb = *(const unsigned int*)(Pr + 2*N_ + n0);
    unsigned int vc = *(const unsigned int*)(Pr + 3*N_ + n0);
    unsigned int ow = 0;
    #pragma unroll
    for (int j = 0; j < 2; j++){
      float pin  = bf2f((unsigned short)(j ? (vp>>16) : (vp & 0xffffu)));
      float draw = bf2f((unsigned short)(j ? (vd>>16) : (vd & 0xffffu))) + bd[j];
      float braw = bf2f((unsigned short)(j ? (vb>>16) : (vb & 0xffffu))) + bb[j];
      float craw = bf2f((unsigned short)(j ? (vc>>16) : (vc & 0xffffu))) + bc[j];
      float a, bu, c;
      abc_from(pin, draw, braw, craw, alpha[j], ginv, a, bu, c);
      float yv = c * z[j];
      z[j] = fmaf(a, z[j], bu);
      ow |= ((unsigned int)f2bf(yv)) << (16*j);
    }
    *(unsigned int*)Y = ow;
    Y += N_;
    Pr += 4*N_;
  }
}

extern "C" void kernel_launch(void* const* d_in, const int* in_sizes, int n_in,
                              void* d_out, int out_size, void* d_ws, size_t ws_size,
                              hipStream_t stream)
{
  const float* u    = (const float*)d_in[0];
  const float* z0   = (const float*)d_in[1];
  const float* Win  = (const float*)d_in[2];
  const float* Wout = (const float*)d_in[3];
  const float* pnw  = (const float*)d_in[4];
  const float* pnb  = (const float*)d_in[5];
  const float* alog = (const float*)d_in[6];
  const float* dbias= (const float*)d_in[7];
  const float* lgam = (const float*)d_in[8];

  char* ws = (char*)d_ws;
  size_t off = 0;
  auto alloc = [&](size_t bytes) -> void* {
    void* p = ws + off;
    off += (bytes + 255) & ~(size_t)255;
    return p;
  };
  float*          sc     = (float*)         alloc(1024);
  unsigned short* u16    = (unsigned short*)alloc((size_t)8192*1024*2);
  unsigned short* Wcat16 = (unsigned short*)alloc((size_t)4096*1024*2);
  unsigned short* Wout16 = (unsigned short*)alloc((size_t)1024*1024*2);
  unsigned short* P16    = (unsigned short*)alloc((size_t)8192*4096*2);
  unsigned short* yh16   = (unsigned short*)alloc((size_t)8192*1024*2);
  unsigned short* Hping  = (unsigned short*)alloc((size_t)2*1024*1024*2);
  unsigned short* Hpong  = (unsigned short*)alloc((size_t)2*1024*1024*2);
  float*          Asum   = (float*)alloc((size_t)B_*NCH*N_*4);
  float*          Ssum   = (float*)alloc((size_t)B_*NCH*N_*4);
  float*          Zent   = (float*)alloc((size_t)B_*NCH*N_*4);

  k_convert_all<<<CONV_BLOCKS, 256, 0, stream>>>(u, Win, pnw, Wout, u16, Wcat16, Wout16, sc);

  // spectral-norm chains: gram (step 0) + SQN trace-normalized squarings; frob fused in last step
  dim3 gsq(16, 16, 2);
  k_sq<<<gsq, 256, 0, stream>>>(Wcat16, Hping, Wout16, Hping + (size_t)1024*1024, sc, 0);
  unsigned short* hin = Hping;
  unsigned short* hout = Hpong;
  for (int s = 1; s <= SQN; s++){
    k_sq<<<gsq, 256, 0, stream>>>(hin, hout, hin + (size_t)1024*1024, hout + (size_t)1024*1024, sc, s);
    unsigned short* t = hin; hin = hout; hout = t;
  }
  k_final<<<1, 64, 0, stream>>>(sc);

  // P = u @ [W_in; pn_w]^T  (bf16 out, no scale — sc[0] applied in pass1/pass3)
  dim3 g1(4096/128, 8192/128, 1);
  k_gemm<1><<<g1, 256, 0, stream>>>(u16, Wcat16, P16, 8192, 4096, 1024, sc, -1);

  dim3 gp1(NCH, N_/512, B_);
  k_pass1<<<gp1, 256, 0, stream>>>(P16, alog, dbias, pnb, lgam, sc, Asum, Ssum);
  dim3 gp2(N_/256, B_);
  k_pass2<<<gp2, 256, 0, stream>>>(Asum, Ssum, z0, Zent);
  k_pass3<<<gp1, 256, 0, stream>>>(P16, alog, dbias, pnb, lgam, sc, Zent, yh16);

  // y = (y_hat @ W_out^T) * sc[1]  (fp32 out)
  dim3 g2(1024/128, 8192/128, 1);
  k_gemm<0><<<g2, 256, 0, stream>>>(yh16, Wout16, d_out, 8192, 1024, 1024, sc, 1);
}